// Round 2
// baseline (283.817 us; speedup 1.0000x reference)
//
#include <hip/hip_runtime.h>
#include <math.h>

// AttentionDownSample: fm [8,128,256,256] f32, Wq/Wk [32,128] f32
// out [8,128,128,128] f32.
// Block = 64 output positions (fixed b,h; w0..w0+63). Stage the full
// 128-channel input tile (2 rows x 128 cols = 32768 floats = 128 KB) into LDS
// via global_load_lds (32 chunks x 4 KB), pipelined with phase A. Then:
//   phase A: Q[r][p]    = sum_c WqT'[c][r] * (v0+v1+v2+v3)    (r split 4-way over waves)
//   phase B: logit[p][s]= sum_c (sum_r Q[r]*WkT[c][r]) * v_s  (c split 4-way over waves)
//   softmax over s (4 window elems)
//   phase C: out[c][p]  = sum_s attn[s] * v_s                 (c split 4-way)
// WqT has 1/(4*sqrt(32)) folded in (pool-mean + reference scaling).
//
// LDS tile layout: tile[c*256 + row*128 + x], x = input col - 2*w0 (0..127).
// Position p uses x = 2p, 2p+1 from both rows; window order s = (row,colpar):
// s0=(0,2p) s1=(0,2p+1) s2=(1,2p) s3=(1,2p+1) — matches _to_grid.

typedef const __attribute__((address_space(1))) void* gas_t;
typedef __attribute__((address_space(3))) void* las_t;

__global__ __launch_bounds__(256) void wt_kernel(const float* __restrict__ Wq,
                                                 const float* __restrict__ Wk,
                                                 float* __restrict__ ws) {
  int t = blockIdx.x * 256 + threadIdx.x;  // 4096 threads, one (c,r) each
  if (t < 4096) {
    int c = t >> 5, r = t & 31;
    ws[c * 32 + r]        = Wq[r * 128 + c] * (0.25f / sqrtf(32.0f));
    ws[4096 + c * 32 + r] = Wk[r * 128 + c];
  }
}

__global__ __launch_bounds__(256, 1) void attn_main(const float* __restrict__ fm,
                                                    const float* __restrict__ ws,
                                                    float* __restrict__ out) {
  extern __shared__ float smem[];
  float* tile = smem;              // [128 c][2 row][128 x] floats (128 KB)
  float* Qbuf = smem + 32768;      // [32 r][64 p]            (8 KB)
  float* lbuf = smem + 34816;      // [4 g][64 p][4 s]        (4 KB)
  float* abuf = smem + 35840;      // [64 p][4 s]             (1 KB)

  const int tid = threadIdx.x;
  const int p   = tid & 63;                 // output position within tile
  const int qg  = __builtin_amdgcn_readfirstlane(tid >> 6);  // wave id, 0..3

  const unsigned blk = blockIdx.x;          // 2048 = 8 b * 128 h * 2 wtiles
  const int w0 = (blk & 1) * 64;
  const int h  = (blk >> 1) & 127;
  const int b  = blk >> 8;

  // ---- issue all 32 staging loads (16B/thread each, 4 KB/chunk) up front ----
  // chunk i stages channels 4i..4i+3: wave g -> channel 4i+g;
  // lane: row=(tid>>5)&1, qd=tid&31 -> cols 2*w0+4*qd..+3.
  // LDS byte = i*4096 + tid*16  (wave-uniform base + lane*16: OK for load_lds)
  {
    const int c0  = tid >> 6;        // 0..3 (wave id)
    const int row = (tid >> 5) & 1;  // 0..1
    const int qd  = tid & 31;        // float4 index within 128-wide row
    const float* g = fm + ((size_t)(b * 128 + c0) * 65536 +
                           (size_t)(2 * h + row) * 256 + 2 * w0 + 4 * qd);
    char* l = (char*)tile + tid * 16;
#pragma unroll
    for (int i = 0; i < 32; ++i) {
      __builtin_amdgcn_global_load_lds((gas_t)(g + (size_t)i * 4 * 65536),
                                       (las_t)(l + i * 4096), 16, 0, 0);
    }
  }

  // ---- phase A: Q accumulation, chunk-pipelined against staging ----
  // group k consumes channels 16k..16k+15 = staging chunks 4k..4k+3;
  // after all 32 issued, wait until oldest 4(k+1) land: vmcnt(28-4k).
  const float* wq = ws + qg * 8;           // WqT[c][qg*8 + j]
  float qa[8] = {0, 0, 0, 0, 0, 0, 0, 0};
#pragma unroll
  for (int k = 0; k < 8; ++k) {
    switch (k) {
      case 0: asm volatile("s_waitcnt vmcnt(28)" ::: "memory"); break;
      case 1: asm volatile("s_waitcnt vmcnt(24)" ::: "memory"); break;
      case 2: asm volatile("s_waitcnt vmcnt(20)" ::: "memory"); break;
      case 3: asm volatile("s_waitcnt vmcnt(16)" ::: "memory"); break;
      case 4: asm volatile("s_waitcnt vmcnt(12)" ::: "memory"); break;
      case 5: asm volatile("s_waitcnt vmcnt(8)"  ::: "memory"); break;
      case 6: asm volatile("s_waitcnt vmcnt(4)"  ::: "memory"); break;
      case 7: asm volatile("s_waitcnt vmcnt(0)"  ::: "memory"); break;
    }
    __builtin_amdgcn_s_barrier();
    asm volatile("" ::: "memory");
#pragma unroll
    for (int i = 0; i < 16; ++i) {
      const int c = k * 16 + i;
      const float2 va = *(const float2*)(tile + c * 256 + 2 * p);        // row0: v0,v1
      const float2 vb = *(const float2*)(tile + c * 256 + 128 + 2 * p);  // row1: v2,v3
      const float ps = (va.x + va.y) + (vb.x + vb.y);
#pragma unroll
      for (int j = 0; j < 8; ++j)
        qa[j] = fmaf(wq[c * 32 + j], ps, qa[j]);
    }
  }
#pragma unroll
  for (int j = 0; j < 8; ++j)
    Qbuf[(qg * 8 + j) * 64 + p] = qa[j];
  __syncthreads();

  // ---- phase B: logits ----
  float Qreg[32];
#pragma unroll
  for (int r = 0; r < 32; ++r) Qreg[r] = Qbuf[r * 64 + p];

  const int cB = qg * 32;
  float l0 = 0.f, l1 = 0.f, l2 = 0.f, l3 = 0.f;
#pragma unroll 2
  for (int i = 0; i < 32; ++i) {
    const int c = cB + i;
    const float2 va = *(const float2*)(tile + c * 256 + 2 * p);
    const float2 vb = *(const float2*)(tile + c * 256 + 128 + 2 * p);
    float t0 = 0.f, t1 = 0.f, t2 = 0.f, t3 = 0.f;
#pragma unroll
    for (int r = 0; r < 32; r += 4) {
      t0 = fmaf(Qreg[r + 0], ws[4096 + c * 32 + r + 0], t0);
      t1 = fmaf(Qreg[r + 1], ws[4096 + c * 32 + r + 1], t1);
      t2 = fmaf(Qreg[r + 2], ws[4096 + c * 32 + r + 2], t2);
      t3 = fmaf(Qreg[r + 3], ws[4096 + c * 32 + r + 3], t3);
    }
    const float tv = (t0 + t1) + (t2 + t3);
    l0 = fmaf(tv, va.x, l0);
    l1 = fmaf(tv, va.y, l1);
    l2 = fmaf(tv, vb.x, l2);
    l3 = fmaf(tv, vb.y, l3);
  }
  *(float4*)(lbuf + (qg * 64 + p) * 4) = make_float4(l0, l1, l2, l3);
  __syncthreads();

  // ---- softmax over the 4 window slots (one thread per position) ----
  if (tid < 64) {
    float4 s0 = *(const float4*)(lbuf + (0 * 64 + tid) * 4);
    float4 s1 = *(const float4*)(lbuf + (1 * 64 + tid) * 4);
    float4 s2 = *(const float4*)(lbuf + (2 * 64 + tid) * 4);
    float4 s3 = *(const float4*)(lbuf + (3 * 64 + tid) * 4);
    float L0 = ((s0.x + s1.x) + (s2.x + s3.x));
    float L1 = ((s0.y + s1.y) + (s2.y + s3.y));
    float L2 = ((s0.z + s1.z) + (s2.z + s3.z));
    float L3 = ((s0.w + s1.w) + (s2.w + s3.w));
    float m = fmaxf(fmaxf(L0, L1), fmaxf(L2, L3));
    float e0 = __expf(L0 - m), e1 = __expf(L1 - m);
    float e2 = __expf(L2 - m), e3 = __expf(L3 - m);
    float inv = 1.0f / ((e0 + e1) + (e2 + e3));
    *(float4*)(abuf + tid * 4) = make_float4(e0 * inv, e1 * inv, e2 * inv, e3 * inv);
  }
  __syncthreads();

  // ---- phase C: weighted sum -> out ----
  const float4 at = *(const float4*)(abuf + p * 4);
  float* op = out + ((size_t)(b * 128 + cB) * 16384 + (size_t)h * 128 + w0 + p);
#pragma unroll 4
  for (int i = 0; i < 32; ++i) {
    const int c = cB + i;
    const float2 va = *(const float2*)(tile + c * 256 + 2 * p);
    const float2 vb = *(const float2*)(tile + c * 256 + 128 + 2 * p);
    float o = fmaf(at.x, va.x, fmaf(at.y, va.y, fmaf(at.z, vb.x, at.w * vb.y)));
    op[(size_t)i * 16384] = o;
  }
}

extern "C" void kernel_launch(void* const* d_in, const int* in_sizes, int n_in,
                              void* d_out, int out_size, void* d_ws, size_t ws_size,
                              hipStream_t stream) {
  const float* fm = (const float*)d_in[0];
  const float* Wq = (const float*)d_in[1];
  const float* Wk = (const float*)d_in[2];
  float* outp = (float*)d_out;
  float* ws = (float*)d_ws;

  const int smem_bytes = 36096 * 4;  // 141 KB
  (void)hipFuncSetAttribute((const void*)attn_main,
                            hipFuncAttributeMaxDynamicSharedMemorySize, smem_bytes);

  wt_kernel<<<16, 256, 0, stream>>>(Wq, Wk, ws);
  attn_main<<<2048, 256, smem_bytes, stream>>>(fm, ws, outp);
}

// Round 3
// 222.714 us; speedup vs baseline: 1.2744x; 1.2744x over previous
//
#include <hip/hip_runtime.h>
#include <math.h>

// AttentionDownSample: fm [8,128,256,256] f32, Wq/Wk [32,128] f32
// out [8,128,128,128] f32.
// Block = 64 output positions (fixed b,h; w0..w0+63), 512 threads (8 waves).
// Stage full 128-channel tile (2 rows x 128 cols = 128 KB) into LDS via
// global_load_lds (16 chunks x 8 KB), pipelined with phase A:
//   phase A: wave (gr=w&3, gc=w>>2) accumulates partial Q[r=gr*8..+7] over
//            channels c = 16m + 8*gc + e (parity-interleaved with staging).
//   Qpart[2][32][64] summed during phase B's Q load.
//   phase B: wave w handles c in [16w,16w+16): t[c]=sum_r Q[r]*WkT[c][r],
//            logits_s += t[c]*v_s.
//   softmax over s (4 window elems), then
//   phase C: out[c][p] = sum_s attn[s]*v_s, c split 16/wave.
// WqT has 1/(4*sqrt(32)) folded in. Weight reads are wave-uniform -> s_load
// (lgkmcnt), so staging vmcnt counts stay exact.

typedef const __attribute__((address_space(1))) void* gas_t;
typedef __attribute__((address_space(3))) void* las_t;

__global__ __launch_bounds__(256) void wt_kernel(const float* __restrict__ Wq,
                                                 const float* __restrict__ Wk,
                                                 float* __restrict__ ws) {
  int t = blockIdx.x * 256 + threadIdx.x;  // 4096 threads, one (c,r) each
  if (t < 4096) {
    int c = t >> 5, r = t & 31;
    ws[c * 32 + r]        = Wq[r * 128 + c] * (0.25f / sqrtf(32.0f));
    ws[4096 + c * 32 + r] = Wk[r * 128 + c];
  }
}

__global__ __launch_bounds__(512, 2) __attribute__((amdgpu_waves_per_eu(2, 2)))
void attn_main(const float* __restrict__ fm,
               const float* __restrict__ ws,
               float* __restrict__ out) {
  extern __shared__ float smem[];
  float* tile  = smem;              // [128 c][2 row][128 x]  (128 KB)
  float* Qpart = smem + 32768;      // [2 gc][32 r][64 p]     (16 KB)
  float* lbuf  = smem + 36864;      // [8 w][64 p][4 s]       (8 KB)
  float* abuf  = smem + 38912;      // [64 p][4 s]            (1 KB)

  const int tid  = threadIdx.x;
  const int p    = tid & 63;                                   // position
  const int w    = __builtin_amdgcn_readfirstlane(tid >> 6);   // wave 0..7

  const unsigned blk = blockIdx.x;  // 2048 = 8 b * 128 h * 2 wtiles
  const int w0 = (blk & 1) * 64;
  const int h  = (blk >> 1) & 127;
  const int b  = blk >> 8;

  // ---- issue all 16 staging loads (16B/thread, 8 KB/chunk) up front ----
  // chunk i covers channels 8i..8i+7; wave w stages channel 8i+w.
  // lane: row=p>>5, qd=p&31 -> cols 2*w0+4*qd..+3.
  // LDS byte = i*8192 + tid*16 (wave-uniform base + lane*16).
  {
    const int row = p >> 5;
    const int qd  = p & 31;
    const float* g = fm + ((size_t)(b * 128 + w) * 65536 +
                           (size_t)(2 * h + row) * 256 + 2 * w0 + 4 * qd);
    char* l = (char*)tile + tid * 16;
#pragma unroll
    for (int i = 0; i < 16; ++i) {
      __builtin_amdgcn_global_load_lds((gas_t)(g + (size_t)i * 8 * 65536),
                                       (las_t)(l + i * 8192), 16, 0, 0);
    }
  }

  // ---- phase A: partial Q, pipelined against staging ----
  // group m consumes channels 16m..16m+15 = staging chunks 2m, 2m+1;
  // wave handles its 8 channels: c = 16m + 8*gc + e.
  const int gr = w & 3, gc = w >> 2;
  const float* wqb = ws + gr * 8;       // WqT[c][gr*8 + j]
  float qa[8] = {0, 0, 0, 0, 0, 0, 0, 0};
#pragma unroll
  for (int m = 0; m < 8; ++m) {
    switch (m) {  // wait until chunks 0..2m+1 landed: vmcnt(14-2m)
      case 0: asm volatile("s_waitcnt vmcnt(14)" ::: "memory"); break;
      case 1: asm volatile("s_waitcnt vmcnt(12)" ::: "memory"); break;
      case 2: asm volatile("s_waitcnt vmcnt(10)" ::: "memory"); break;
      case 3: asm volatile("s_waitcnt vmcnt(8)"  ::: "memory"); break;
      case 4: asm volatile("s_waitcnt vmcnt(6)"  ::: "memory"); break;
      case 5: asm volatile("s_waitcnt vmcnt(4)"  ::: "memory"); break;
      case 6: asm volatile("s_waitcnt vmcnt(2)"  ::: "memory"); break;
      case 7: asm volatile("s_waitcnt vmcnt(0)"  ::: "memory"); break;
    }
    __builtin_amdgcn_s_barrier();
#pragma unroll
    for (int e = 0; e < 8; ++e) {
      const int c = 16 * m + 8 * gc + e;
      const float2 va = *(const float2*)(tile + c * 256 + 2 * p);        // row0
      const float2 vb = *(const float2*)(tile + c * 256 + 128 + 2 * p);  // row1
      const float ps = (va.x + va.y) + (vb.x + vb.y);
#pragma unroll
      for (int j = 0; j < 8; ++j)
        qa[j] = fmaf(wqb[c * 32 + j], ps, qa[j]);
    }
  }
#pragma unroll
  for (int j = 0; j < 8; ++j)
    Qpart[gc * 2048 + (gr * 8 + j) * 64 + p] = qa[j];
  __syncthreads();

  // ---- phase B: logits (wave w: channels 16w..16w+15) ----
  float Qreg[32];
#pragma unroll
  for (int r = 0; r < 32; ++r)
    Qreg[r] = Qpart[r * 64 + p] + Qpart[2048 + r * 64 + p];

  const int cB = w * 16;
  const float* wkb = ws + 4096;
  float l0 = 0.f, l1 = 0.f, l2 = 0.f, l3 = 0.f;
#pragma unroll 2
  for (int i = 0; i < 16; ++i) {
    const int c = cB + i;
    const float2 va = *(const float2*)(tile + c * 256 + 2 * p);
    const float2 vb = *(const float2*)(tile + c * 256 + 128 + 2 * p);
    float t0 = 0.f, t1 = 0.f, t2 = 0.f, t3 = 0.f;
#pragma unroll
    for (int r = 0; r < 32; r += 4) {
      t0 = fmaf(Qreg[r + 0], wkb[c * 32 + r + 0], t0);
      t1 = fmaf(Qreg[r + 1], wkb[c * 32 + r + 1], t1);
      t2 = fmaf(Qreg[r + 2], wkb[c * 32 + r + 2], t2);
      t3 = fmaf(Qreg[r + 3], wkb[c * 32 + r + 3], t3);
    }
    const float tv = (t0 + t1) + (t2 + t3);
    l0 = fmaf(tv, va.x, l0);
    l1 = fmaf(tv, va.y, l1);
    l2 = fmaf(tv, vb.x, l2);
    l3 = fmaf(tv, vb.y, l3);
  }
  *(float4*)(lbuf + (w * 64 + p) * 4) = make_float4(l0, l1, l2, l3);
  __syncthreads();

  // ---- softmax over the 4 window slots (one thread per position) ----
  if (tid < 64) {
    float L0 = 0.f, L1 = 0.f, L2 = 0.f, L3 = 0.f;
#pragma unroll
    for (int g = 0; g < 8; ++g) {
      float4 s = *(const float4*)(lbuf + (g * 64 + tid) * 4);
      L0 += s.x; L1 += s.y; L2 += s.z; L3 += s.w;
    }
    float mx = fmaxf(fmaxf(L0, L1), fmaxf(L2, L3));
    float e0 = __expf(L0 - mx), e1 = __expf(L1 - mx);
    float e2 = __expf(L2 - mx), e3 = __expf(L3 - mx);
    float inv = 1.0f / ((e0 + e1) + (e2 + e3));
    *(float4*)(abuf + tid * 4) = make_float4(e0 * inv, e1 * inv, e2 * inv, e3 * inv);
  }
  __syncthreads();

  // ---- phase C: weighted sum -> out (wave w: channels 16w..16w+15) ----
  const float4 at = *(const float4*)(abuf + p * 4);
  float* op = out + ((size_t)(b * 128 + cB) * 16384 + (size_t)h * 128 + w0 + p);
#pragma unroll 4
  for (int i = 0; i < 16; ++i) {
    const int c = cB + i;
    const float2 va = *(const float2*)(tile + c * 256 + 2 * p);
    const float2 vb = *(const float2*)(tile + c * 256 + 128 + 2 * p);
    float o = fmaf(at.x, va.x, fmaf(at.y, va.y, fmaf(at.z, vb.x, at.w * vb.y)));
    op[(size_t)i * 16384] = o;
  }
}

extern "C" void kernel_launch(void* const* d_in, const int* in_sizes, int n_in,
                              void* d_out, int out_size, void* d_ws, size_t ws_size,
                              hipStream_t stream) {
  const float* fm = (const float*)d_in[0];
  const float* Wq = (const float*)d_in[1];
  const float* Wk = (const float*)d_in[2];
  float* outp = (float*)d_out;
  float* ws = (float*)d_ws;

  const int smem_bytes = 39168 * 4;  // 153 KB
  (void)hipFuncSetAttribute((const void*)attn_main,
                            hipFuncAttributeMaxDynamicSharedMemorySize, smem_bytes);

  wt_kernel<<<16, 256, 0, stream>>>(Wq, Wk, ws);
  attn_main<<<2048, 512, smem_bytes, stream>>>(fm, ws, outp);
}

// Round 4
// 154.816 us; speedup vs baseline: 1.8333x; 1.4386x over previous
//
#include <hip/hip_runtime.h>
#include <math.h>

// AttentionDownSample: fm [8,128,256,256] f32, Wq/Wk [32,128] f32
// out [8,128,128,128] f32.
// Block = 64 output positions (fixed b,h; w0..w0+63), 512 threads (8 waves).
// KEY CHANGE vs r3: weights live in LDS (wbuf), not SMEM — hot loops are pure
// ds_read + VALU so the compiler can use counted lgkmcnt waits instead of
// draining lgkmcnt(0) on every mixed SMEM/DS use (the r3 latency killer).
//   stage:   2x WqT (16 KB) + 16x tile chunk (8 KB each) via global_load_lds
//   phase A: wave (gr=w&3, gc=w>>2): partial Q[gr*8..+7] over c=16m+8gc+e,
//            pipelined against staging with vmcnt(14-2m).
//   WkT re-staged into wbuf (overlapped with Qpart in-place reduction).
//   phase B: wave w: c in [16w,16w+16): t[c]=sum_r Q[r]*WkT[c][r],
//            logits_s += t[c]*v_s.
//   softmax over s=4, phase C: out = sum_s attn_s * v_s.
// WqT has 1/(4*sqrt(32)) folded in.
// LDS: tile[128c][2row][128x] 128 KB | wbuf 16 KB (WqT->WkT, later abuf)
//      Qpart [32r][64p] 8 KB (later lbuf) = 152 KB total.

typedef const __attribute__((address_space(1))) void* gas_t;
typedef __attribute__((address_space(3))) void* las_t;

__global__ __launch_bounds__(256) void wt_kernel(const float* __restrict__ Wq,
                                                 const float* __restrict__ Wk,
                                                 float* __restrict__ ws) {
  int t = blockIdx.x * 256 + threadIdx.x;  // 4096 threads, one (c,r) each
  if (t < 4096) {
    int c = t >> 5, r = t & 31;
    ws[c * 32 + r]        = Wq[r * 128 + c] * (0.25f / sqrtf(32.0f));
    ws[4096 + c * 32 + r] = Wk[r * 128 + c];
  }
}

__global__ __launch_bounds__(512, 2)
void attn_main(const float* __restrict__ fm,
               const float* __restrict__ ws,
               float* __restrict__ out) {
  extern __shared__ float smem[];
  float* tile  = smem;              // [128][2][128] floats   (128 KB)
  float* wbuf  = smem + 32768;      // 4096 f: WqT then WkT   (16 KB)
  float* Qpart = smem + 36864;      // [32 r][64 p]           (8 KB)
  float* lbuf  = smem + 36864;      // alias Qpart: [8 w][64 p][4 s]
  float* abuf  = smem + 32768;      // alias wbuf:  [64 p][4 s]

  const int tid = threadIdx.x;
  const int p   = tid & 63;                                   // position
  const int w   = __builtin_amdgcn_readfirstlane(tid >> 6);   // wave 0..7

  const unsigned blk = blockIdx.x;  // 2048 = 8 b * 128 h * 2 wtiles
  const int w0 = (blk & 1) * 64;
  const int h  = (blk >> 1) & 127;
  const int b  = blk >> 8;

  // ---- staging: issues 0,1 = WqT (16 KB); issues 2..17 = tile chunks ----
  {
    const char* wsrc = (const char*)ws;     // WqT at bytes [0, 16384)
    char* wdst = (char*)wbuf + tid * 16;
#pragma unroll
    for (int j = 0; j < 2; ++j) {
      __builtin_amdgcn_global_load_lds((gas_t)(wsrc + tid * 16 + j * 8192),
                                       (las_t)(wdst + j * 8192), 16, 0, 0);
    }
  }
  {
    // chunk i covers channels 8i..8i+7; wave w stages channel 8i+w.
    const int row = p >> 5;
    const int qd  = p & 31;
    const float* g = fm + ((size_t)(b * 128 + w) * 65536 +
                           (size_t)(2 * h + row) * 256 + 2 * w0 + 4 * qd);
    char* l = (char*)tile + tid * 16;
#pragma unroll
    for (int i = 0; i < 16; ++i) {
      __builtin_amdgcn_global_load_lds((gas_t)(g + (size_t)i * 8 * 65536),
                                       (las_t)(l + i * 8192), 16, 0, 0);
    }
  }

  // ---- phase A: partial Q, pipelined against staging ----
  // group m needs issues 0..3+2m done -> vmcnt(14-2m).
  const int gr = w & 3, gc = w >> 2;
  float qa[8] = {0, 0, 0, 0, 0, 0, 0, 0};
#pragma unroll
  for (int m = 0; m < 8; ++m) {
    switch (m) {
      case 0: asm volatile("s_waitcnt vmcnt(14)" ::: "memory"); break;
      case 1: asm volatile("s_waitcnt vmcnt(12)" ::: "memory"); break;
      case 2: asm volatile("s_waitcnt vmcnt(10)" ::: "memory"); break;
      case 3: asm volatile("s_waitcnt vmcnt(8)"  ::: "memory"); break;
      case 4: asm volatile("s_waitcnt vmcnt(6)"  ::: "memory"); break;
      case 5: asm volatile("s_waitcnt vmcnt(4)"  ::: "memory"); break;
      case 6: asm volatile("s_waitcnt vmcnt(2)"  ::: "memory"); break;
      case 7: asm volatile("s_waitcnt vmcnt(0)"  ::: "memory"); break;
    }
    __builtin_amdgcn_s_barrier();
#pragma unroll
    for (int e = 0; e < 8; ++e) {
      const int c = 16 * m + 8 * gc + e;
      const float2 va = *(const float2*)(tile + c * 256 + 2 * p);        // row0
      const float2 vb = *(const float2*)(tile + c * 256 + 128 + 2 * p);  // row1
      const float ps = (va.x + va.y) + (vb.x + vb.y);
      const float4 wa = *(const float4*)(wbuf + c * 32 + gr * 8);
      const float4 wb = *(const float4*)(wbuf + c * 32 + gr * 8 + 4);
      qa[0] = fmaf(wa.x, ps, qa[0]);
      qa[1] = fmaf(wa.y, ps, qa[1]);
      qa[2] = fmaf(wa.z, ps, qa[2]);
      qa[3] = fmaf(wa.w, ps, qa[3]);
      qa[4] = fmaf(wb.x, ps, qa[4]);
      qa[5] = fmaf(wb.y, ps, qa[5]);
      qa[6] = fmaf(wb.z, ps, qa[6]);
      qa[7] = fmaf(wb.w, ps, qa[7]);
    }
  }
  __syncthreads();  // all waves done reading WqT + tile group 7

  // ---- re-stage WkT (bytes [16384,32768) of ws) into wbuf ----
  {
    const char* wsrc = (const char*)ws + 16384;
    char* wdst = (char*)wbuf + tid * 16;
#pragma unroll
    for (int j = 0; j < 2; ++j) {
      __builtin_amdgcn_global_load_lds((gas_t)(wsrc + tid * 16 + j * 8192),
                                       (las_t)(wdst + j * 8192), 16, 0, 0);
    }
  }

  // ---- Qpart in-place reduction (overlaps WkT staging) ----
  if (gc == 1) {
#pragma unroll
    for (int j = 0; j < 8; ++j)
      Qpart[(gr * 8 + j) * 64 + p] = qa[j];
  }
  __syncthreads();
  if (gc == 0) {
#pragma unroll
    for (int j = 0; j < 8; ++j)
      Qpart[(gr * 8 + j) * 64 + p] += qa[j];
  }
  __syncthreads();

  float Qreg[32];
#pragma unroll
  for (int r = 0; r < 32; ++r) Qreg[r] = Qpart[r * 64 + p];
  asm volatile("s_waitcnt vmcnt(0)" ::: "memory");  // WkT landed
  __syncthreads();  // Qreg reads done -> lbuf may overwrite Qpart

  // ---- phase B: logits (wave w: channels 16w..16w+15) ----
  const int cB = w * 16;
  float l0 = 0.f, l1 = 0.f, l2 = 0.f, l3 = 0.f;
#pragma unroll 2
  for (int i = 0; i < 16; ++i) {
    const int c = cB + i;
    const float2 va = *(const float2*)(tile + c * 256 + 2 * p);
    const float2 vb = *(const float2*)(tile + c * 256 + 128 + 2 * p);
    float t0 = 0.f, t1 = 0.f, t2 = 0.f, t3 = 0.f;
#pragma unroll
    for (int rr = 0; rr < 32; rr += 8) {
      const float4 ka = *(const float4*)(wbuf + c * 32 + rr);
      const float4 kb = *(const float4*)(wbuf + c * 32 + rr + 4);
      t0 = fmaf(Qreg[rr + 0], ka.x, t0);
      t1 = fmaf(Qreg[rr + 1], ka.y, t1);
      t2 = fmaf(Qreg[rr + 2], ka.z, t2);
      t3 = fmaf(Qreg[rr + 3], ka.w, t3);
      t0 = fmaf(Qreg[rr + 4], kb.x, t0);
      t1 = fmaf(Qreg[rr + 5], kb.y, t1);
      t2 = fmaf(Qreg[rr + 6], kb.z, t2);
      t3 = fmaf(Qreg[rr + 7], kb.w, t3);
    }
    const float tv = (t0 + t1) + (t2 + t3);
    l0 = fmaf(tv, va.x, l0);
    l1 = fmaf(tv, va.y, l1);
    l2 = fmaf(tv, vb.x, l2);
    l3 = fmaf(tv, vb.y, l3);
  }
  *(float4*)(lbuf + (w * 64 + p) * 4) = make_float4(l0, l1, l2, l3);
  __syncthreads();  // lbuf ready; all wbuf(WkT) reads done

  // ---- softmax over the 4 window slots (one thread per position) ----
  if (tid < 64) {
    float L0 = 0.f, L1 = 0.f, L2 = 0.f, L3 = 0.f;
#pragma unroll
    for (int g = 0; g < 8; ++g) {
      float4 s = *(const float4*)(lbuf + (g * 64 + tid) * 4);
      L0 += s.x; L1 += s.y; L2 += s.z; L3 += s.w;
    }
    float mx = fmaxf(fmaxf(L0, L1), fmaxf(L2, L3));
    float e0 = __expf(L0 - mx), e1 = __expf(L1 - mx);
    float e2 = __expf(L2 - mx), e3 = __expf(L3 - mx);
    float inv = 1.0f / ((e0 + e1) + (e2 + e3));
    *(float4*)(abuf + tid * 4) = make_float4(e0 * inv, e1 * inv, e2 * inv, e3 * inv);
  }
  __syncthreads();

  // ---- phase C: weighted sum -> out (wave w: channels 16w..16w+15) ----
  const float4 at = *(const float4*)(abuf + p * 4);
  float* op = out + ((size_t)(b * 128 + cB) * 16384 + (size_t)h * 128 + w0 + p);
#pragma unroll 4
  for (int i = 0; i < 16; ++i) {
    const int c = cB + i;
    const float2 va = *(const float2*)(tile + c * 256 + 2 * p);
    const float2 vb = *(const float2*)(tile + c * 256 + 128 + 2 * p);
    float o = fmaf(at.x, va.x, fmaf(at.y, va.y, fmaf(at.z, vb.x, at.w * vb.y)));
    op[(size_t)i * 16384] = o;
  }
}

extern "C" void kernel_launch(void* const* d_in, const int* in_sizes, int n_in,
                              void* d_out, int out_size, void* d_ws, size_t ws_size,
                              hipStream_t stream) {
  const float* fm = (const float*)d_in[0];
  const float* Wq = (const float*)d_in[1];
  const float* Wk = (const float*)d_in[2];
  float* outp = (float*)d_out;
  float* ws = (float*)d_ws;

  const int smem_bytes = 38912 * 4;  // 152 KB
  (void)hipFuncSetAttribute((const void*)attn_main,
                            hipFuncAttributeMaxDynamicSharedMemorySize, smem_bytes);

  wt_kernel<<<16, 256, 0, stream>>>(Wq, Wk, ws);
  attn_main<<<2048, 512, smem_bytes, stream>>>(fm, ws, outp);
}

// Round 5
// 149.312 us; speedup vs baseline: 1.9008x; 1.0369x over previous
//
#include <hip/hip_runtime.h>
#include <math.h>

// AttentionDownSample: fm [8,128,256,256] f32, Wq/Wk [32,128] f32
// out [8,128,128,128] f32.
//
// r5 redesign: NO fm tile in LDS. Three register-resident passes over fm,
// re-reads hit L2 (per-block working set 256 KB; ~8 blocks/XCD share 4 MB L2).
// Weights are wave-uniform scalar loads (SMEM/lgkmcnt); fm loads are plain
// global loads (vmcnt) — separate counters, both counted by the compiler.
//
// Decomposition per position (h,w):  u[c] = v0+v1+v2+v3 (window sum)
//   Q[r]    = sum_c WqT'[c][r] * u[c]          (WqT' has 0.25/sqrt(32) folded)
//   t[c]    = sum_r Q[r] * WkT[c][r]
//   logit_s = sum_c t[c] * v_s[c]
//   out[c]  = sum_s softmax(logit)_s * v_s[c]
//
// Block = 256 threads = 128 positions (one b,h row, w=0..127) x 2 channel
// halves (half = tid>>7 -> channels half*64..+63). Q and logits are combined
// across halves via small LDS buffers. Grid = 8b x 128h = 1024 blocks.
// LDS = 32 KB Qpart + 4 KB lbuf + 2 KB abuf = 38 KB -> 4 blocks/CU,
// 16 waves/CU (50% occupancy).

__global__ __launch_bounds__(256) void wt_kernel(const float* __restrict__ Wq,
                                                 const float* __restrict__ Wk,
                                                 float* __restrict__ ws) {
  int t = blockIdx.x * 256 + threadIdx.x;  // 4096 threads, one (c,r) each
  if (t < 4096) {
    int c = t >> 5, r = t & 31;
    ws[c * 32 + r]        = Wq[r * 128 + c] * (0.25f / sqrtf(32.0f));
    ws[4096 + c * 32 + r] = Wk[r * 128 + c];
  }
}

__global__ __launch_bounds__(256, 4)
void attn_main(const float* __restrict__ fm,
               const float* __restrict__ ws,
               float* __restrict__ out) {
  __shared__ float Qpart[2 * 32 * 128];  // [half][r][p]  32 KB
  __shared__ float lbuf[2 * 128 * 4];    // [half][p][s]   4 KB
  __shared__ float abuf[128 * 4];        // [p][s]         2 KB

  const int tid  = threadIdx.x;
  const int p    = tid & 127;                                   // w position
  const int half = __builtin_amdgcn_readfirstlane(tid >> 7);    // channel half
  const int blk  = blockIdx.x;                                  // 1024
  const int h    = blk & 127;
  const int b    = blk >> 7;
  const int cbase = half * 64;

  const float* gbase = fm + ((size_t)(b * 128 + cbase) * 65536) +
                       (size_t)(2 * h) * 256 + 2 * p;
  const float* wq = ws + cbase * 32;          // WqT'[c][r], r contiguous
  const float* wk = ws + 4096 + cbase * 32;   // WkT[c][r]

  // ---- pass 1: Q accumulation over this half's 64 channels ----
  float qa[32];
#pragma unroll
  for (int r = 0; r < 32; ++r) qa[r] = 0.f;
  {
    const float* g = gbase;
#pragma unroll 4
    for (int i = 0; i < 64; ++i) {
      const float2 va = *(const float2*)(g);        // row 2h:   v0,v1
      const float2 vb = *(const float2*)(g + 256);  // row 2h+1: v2,v3
      const float u = (va.x + va.y) + (vb.x + vb.y);
#pragma unroll
      for (int r = 0; r < 32; ++r)
        qa[r] = fmaf(wq[i * 32 + r], u, qa[r]);
      g += 65536;
    }
  }
  // exchange partial Q across halves ([half][r][p]: b32, 2 lanes/bank = free)
#pragma unroll
  for (int r = 0; r < 32; ++r) Qpart[half * 4096 + r * 128 + p] = qa[r];
  __syncthreads();
#pragma unroll
  for (int r = 0; r < 32; ++r) qa[r] += Qpart[(half ^ 1) * 4096 + r * 128 + p];

  // ---- pass 2: logits over this half's channels ----
  float l0 = 0.f, l1 = 0.f, l2 = 0.f, l3 = 0.f;
  {
    const float* g = gbase;
#pragma unroll 2
    for (int i = 0; i < 64; ++i) {
      const float2 va = *(const float2*)(g);
      const float2 vb = *(const float2*)(g + 256);
      float t0 = 0.f, t1 = 0.f, t2 = 0.f, t3 = 0.f;
#pragma unroll
      for (int r = 0; r < 32; r += 4) {
        t0 = fmaf(qa[r + 0], wk[i * 32 + r + 0], t0);
        t1 = fmaf(qa[r + 1], wk[i * 32 + r + 1], t1);
        t2 = fmaf(qa[r + 2], wk[i * 32 + r + 2], t2);
        t3 = fmaf(qa[r + 3], wk[i * 32 + r + 3], t3);
      }
      const float tv = (t0 + t1) + (t2 + t3);
      l0 = fmaf(tv, va.x, l0);
      l1 = fmaf(tv, va.y, l1);
      l2 = fmaf(tv, vb.x, l2);
      l3 = fmaf(tv, vb.y, l3);
      g += 65536;
    }
  }
  *(float4*)(lbuf + (half * 128 + p) * 4) = make_float4(l0, l1, l2, l3);
  __syncthreads();

  // ---- softmax (half 0 combines both halves, broadcasts attn) ----
  if (half == 0) {
    const float4 o = *(const float4*)(lbuf + (128 + p) * 4);
    const float L0 = l0 + o.x, L1 = l1 + o.y, L2 = l2 + o.z, L3 = l3 + o.w;
    const float mx = fmaxf(fmaxf(L0, L1), fmaxf(L2, L3));
    const float e0 = __expf(L0 - mx), e1 = __expf(L1 - mx);
    const float e2 = __expf(L2 - mx), e3 = __expf(L3 - mx);
    const float inv = 1.0f / ((e0 + e1) + (e2 + e3));
    *(float4*)(abuf + p * 4) =
        make_float4(e0 * inv, e1 * inv, e2 * inv, e3 * inv);
  }
  __syncthreads();
  const float4 at = *(const float4*)(abuf + p * 4);

  // ---- pass 3: weighted window sum -> out ----
  {
    const float* g = gbase;
    float* op = out + ((size_t)(b * 128 + cbase) * 16384) + h * 128 + p;
#pragma unroll 4
    for (int i = 0; i < 64; ++i) {
      const float2 va = *(const float2*)(g);
      const float2 vb = *(const float2*)(g + 256);
      *op = fmaf(at.x, va.x, fmaf(at.y, va.y, fmaf(at.z, vb.x, at.w * vb.y)));
      g += 65536;
      op += 16384;
    }
  }
}

extern "C" void kernel_launch(void* const* d_in, const int* in_sizes, int n_in,
                              void* d_out, int out_size, void* d_ws, size_t ws_size,
                              hipStream_t stream) {
  const float* fm = (const float*)d_in[0];
  const float* Wq = (const float*)d_in[1];
  const float* Wk = (const float*)d_in[2];
  float* outp = (float*)d_out;
  float* ws = (float*)d_ws;

  wt_kernel<<<16, 256, 0, stream>>>(Wq, Wk, ws);
  attn_main<<<1024, 256, 0, stream>>>(fm, ws, outp);
}

// Round 6
// 149.047 us; speedup vs baseline: 1.9042x; 1.0018x over previous
//
#include <hip/hip_runtime.h>
#include <math.h>

// AttentionDownSample: fm [8,128,256,256] f32, Wq/Wk [32,128] f32
// out [8,128,128,128] f32.
//
// r6: same 3-pass streaming structure as r5, but LDS slimmed to exactly 20 KB
// -> 8 blocks/CU (2048 thr = 32 waves = 100% occupancy). r5 counters showed
// latency-bound (VALUBusy 13%, HBM 31%, occ 42%): the fix is wave count.
//   - Qpart reduced IN PLACE ([32][128] = 16 KB instead of [2][32][128]).
//   - attn broadcast aliases lbuf (4 KB) -> total 20480 B, 8 x 20 KB = 160 KB.
//   - __launch_bounds__(256,8) pins VGPR <= 64 (r5 used 52).
//   - pass 2 walks channels in REVERSE (MRU-first after pass 1), pass 3
//     forward again (MRU after pass 2) for L2/L3 temporal locality.
//   - output stores nontemporal: don't let 67 MB of writes evict fm from L3.
//
// Decomposition per position (h,w):  u[c] = v0+v1+v2+v3 (window sum)
//   Q[r]    = sum_c WqT'[c][r] * u[c]          (WqT' has 0.25/sqrt(32) folded)
//   t[c]    = sum_r Q[r] * WkT[c][r]
//   logit_s = sum_c t[c] * v_s[c]
//   out[c]  = sum_s softmax(logit)_s * v_s[c]
//
// Block = 256 threads = 128 positions (one b,h row) x 2 channel halves
// (half = tid>>7 -> channels half*64..+63). Weights are wave-uniform scalar
// loads (SMEM/lgkmcnt); fm loads are plain global loads (vmcnt).

__global__ __launch_bounds__(256) void wt_kernel(const float* __restrict__ Wq,
                                                 const float* __restrict__ Wk,
                                                 float* __restrict__ ws) {
  int t = blockIdx.x * 256 + threadIdx.x;  // 4096 threads, one (c,r) each
  if (t < 4096) {
    int c = t >> 5, r = t & 31;
    ws[c * 32 + r]        = Wq[r * 128 + c] * (0.25f / sqrtf(32.0f));
    ws[4096 + c * 32 + r] = Wk[r * 128 + c];
  }
}

__global__ __launch_bounds__(256, 8)
void attn_main(const float* __restrict__ fm,
               const float* __restrict__ ws,
               float* __restrict__ out) {
  __shared__ float Qpart[32 * 128];    // [r][p]  16 KB (in-place reduce)
  __shared__ float lbuf[2 * 128 * 4];  // [half][p][s] 4 KB; attn aliases [0]

  const int tid  = threadIdx.x;
  const int p    = tid & 127;                                   // w position
  const int half = __builtin_amdgcn_readfirstlane(tid >> 7);    // channel half
  const int blk  = blockIdx.x;                                  // 1024
  const int h    = blk & 127;
  const int b    = blk >> 7;
  const int cbase = half * 64;

  const float* gbase = fm + ((size_t)(b * 128 + cbase) * 65536) +
                       (size_t)(2 * h) * 256 + 2 * p;
  const float* wq = ws + cbase * 32;          // WqT'[c][r], r contiguous
  const float* wk = ws + 4096 + cbase * 32;   // WkT[c][r]

  // ---- pass 1: Q accumulation over this half's 64 channels ----
  float qa[32];
#pragma unroll
  for (int r = 0; r < 32; ++r) qa[r] = 0.f;
  {
    const float* g = gbase;
#pragma unroll 4
    for (int i = 0; i < 64; ++i) {
      const float2 va = *(const float2*)(g);        // row 2h:   v0,v1
      const float2 vb = *(const float2*)(g + 256);  // row 2h+1: v2,v3
      const float u = (va.x + va.y) + (vb.x + vb.y);
#pragma unroll
      for (int r = 0; r < 32; ++r)
        qa[r] = fmaf(wq[i * 32 + r], u, qa[r]);
      g += 65536;
    }
  }
  // ---- in-place Q reduce across halves ([r][p]: b32, 2 lanes/bank = free) --
  if (half == 1) {
#pragma unroll
    for (int r = 0; r < 32; ++r) Qpart[r * 128 + p] = qa[r];
  }
  __syncthreads();
  if (half == 0) {
#pragma unroll
    for (int r = 0; r < 32; ++r) {
      const float t = qa[r] + Qpart[r * 128 + p];
      qa[r] = t;
      Qpart[r * 128 + p] = t;
    }
  }
  __syncthreads();
  if (half == 1) {
#pragma unroll
    for (int r = 0; r < 32; ++r) qa[r] = Qpart[r * 128 + p];
  }

  // ---- pass 2: logits over this half's channels (reverse order: MRU) ----
  float l0 = 0.f, l1 = 0.f, l2 = 0.f, l3 = 0.f;
  {
    const float* g = gbase + (size_t)63 * 65536;
#pragma unroll 2
    for (int i = 63; i >= 0; --i) {
      const float2 va = *(const float2*)(g);
      const float2 vb = *(const float2*)(g + 256);
      float t0 = 0.f, t1 = 0.f, t2 = 0.f, t3 = 0.f;
#pragma unroll
      for (int r = 0; r < 32; r += 4) {
        t0 = fmaf(qa[r + 0], wk[i * 32 + r + 0], t0);
        t1 = fmaf(qa[r + 1], wk[i * 32 + r + 1], t1);
        t2 = fmaf(qa[r + 2], wk[i * 32 + r + 2], t2);
        t3 = fmaf(qa[r + 3], wk[i * 32 + r + 3], t3);
      }
      const float tv = (t0 + t1) + (t2 + t3);
      l0 = fmaf(tv, va.x, l0);
      l1 = fmaf(tv, va.y, l1);
      l2 = fmaf(tv, vb.x, l2);
      l3 = fmaf(tv, vb.y, l3);
      g -= 65536;
    }
  }
  *(float4*)(lbuf + (half * 128 + p) * 4) = make_float4(l0, l1, l2, l3);
  __syncthreads();

  // ---- softmax (half 0 combines both halves, broadcasts attn via lbuf[0]) --
  if (half == 0) {
    const float4 o = *(const float4*)(lbuf + (128 + p) * 4);
    const float L0 = l0 + o.x, L1 = l1 + o.y, L2 = l2 + o.z, L3 = l3 + o.w;
    const float mx = fmaxf(fmaxf(L0, L1), fmaxf(L2, L3));
    const float e0 = __expf(L0 - mx), e1 = __expf(L1 - mx);
    const float e2 = __expf(L2 - mx), e3 = __expf(L3 - mx);
    const float inv = 1.0f / ((e0 + e1) + (e2 + e3));
    *(float4*)(lbuf + p * 4) =
        make_float4(e0 * inv, e1 * inv, e2 * inv, e3 * inv);
  }
  __syncthreads();
  const float4 at = *(const float4*)(lbuf + p * 4);

  // ---- pass 3: weighted window sum -> out (forward: MRU after pass 2) ----
  {
    const float* g = gbase;
    float* op = out + ((size_t)(b * 128 + cbase) * 16384) + h * 128 + p;
#pragma unroll 8
    for (int i = 0; i < 64; ++i) {
      const float2 va = *(const float2*)(g);
      const float2 vb = *(const float2*)(g + 256);
      const float o =
          fmaf(at.x, va.x, fmaf(at.y, va.y, fmaf(at.z, vb.x, at.w * vb.y)));
      __builtin_nontemporal_store(o, op);
      g += 65536;
      op += 16384;
    }
  }
}

extern "C" void kernel_launch(void* const* d_in, const int* in_sizes, int n_in,
                              void* d_out, int out_size, void* d_ws, size_t ws_size,
                              hipStream_t stream) {
  const float* fm = (const float*)d_in[0];
  const float* Wq = (const float*)d_in[1];
  const float* Wk = (const float*)d_in[2];
  float* outp = (float*)d_out;
  float* ws = (float*)d_ws;

  wt_kernel<<<16, 256, 0, stream>>>(Wq, Wk, ws);
  attn_main<<<1024, 256, 0, stream>>>(fm, ws, outp);
}

// Round 7
// 146.429 us; speedup vs baseline: 1.9383x; 1.0179x over previous
//
#include <hip/hip_runtime.h>
#include <math.h>

// AttentionDownSample: fm [8,128,256,256] f32, Wq/Wk [32,128] f32
// out [8,128,128,128] f32.
//
// r7: r6's occupancy fix failed because the GRID (1024 blocks) capped CUs at
// 4 blocks each. Now: 2048 blocks x 256 thr; block = 64 positions (one b,h,
// half-w row) x 4 channel groups (32 ch each). 8 blocks/CU x 4 waves = 32
// waves/CU (100%). LDS = Qpart[2][32][64] (16 KB, tree reduce) + lbuf[4][64][4]
// (4 KB) = 20 KB -> LDS allows 8 blocks/CU. Loads explicitly batched 4
// channels deep (8 dwordx2 in flight before any dependent VALU).
//
// Decomposition per position (h,w):  u[c] = v0+v1+v2+v3 (window sum)
//   Q[r]    = sum_c WqT'[c][r] * u[c]       (WqT' has 0.25/sqrt(32) folded)
//   t[c]    = sum_r Q[r] * WkT[c][r]
//   logit_s = sum_c t[c] * v_s[c]
//   out[c]  = sum_s softmax(logit)_s * v_s[c]
// Weights: wave-uniform scalar loads (SMEM/lgkmcnt); fm: global loads (vmcnt).

__global__ __launch_bounds__(256) void wt_kernel(const float* __restrict__ Wq,
                                                 const float* __restrict__ Wk,
                                                 float* __restrict__ ws) {
  int t = blockIdx.x * 256 + threadIdx.x;  // 4096 threads, one (c,r) each
  if (t < 4096) {
    int c = t >> 5, r = t & 31;
    ws[c * 32 + r]        = Wq[r * 128 + c] * (0.25f / sqrtf(32.0f));
    ws[4096 + c * 32 + r] = Wk[r * 128 + c];
  }
}

__global__ __launch_bounds__(256, 8)
void attn_main(const float* __restrict__ fm,
               const float* __restrict__ ws,
               float* __restrict__ out) {
  __shared__ float Qpart[2 * 32 * 64];  // [pair][r][p] 16 KB (tree reduce)
  __shared__ float lbuf[4 * 64 * 4];    // [grp][p][s]   4 KB; attn in [0]

  const int tid = threadIdx.x;
  const int p   = tid & 63;                                   // position
  const int grp = __builtin_amdgcn_readfirstlane(tid >> 6);   // 0..3

  const int blk = blockIdx.x;           // 2048 = 8 b * 128 h * 2 wh
  const int w0  = (blk & 1) * 64;
  const int h   = (blk >> 1) & 127;
  const int b   = blk >> 8;
  const int cb  = grp * 32;             // this group's channel base

  const float* gbase = fm + ((size_t)(b * 128 + cb) * 65536) +
                       (size_t)(2 * h) * 256 + 2 * (w0 + p);
  const float* wq = ws + cb * 32;          // WqT'[c][r], r contiguous
  const float* wk = ws + 4096 + cb * 32;   // WkT[c][r]

  // ---- pass 1: partial Q over this group's 32 channels (batch 4) ----
  float qa[32];
#pragma unroll
  for (int r = 0; r < 32; ++r) qa[r] = 0.f;
  {
    const float* g = gbase;
#pragma unroll 2
    for (int i0 = 0; i0 < 32; i0 += 4) {
      const float2 va0 = *(const float2*)(g + 0 * 65536);
      const float2 vb0 = *(const float2*)(g + 0 * 65536 + 256);
      const float2 va1 = *(const float2*)(g + 1 * 65536);
      const float2 vb1 = *(const float2*)(g + 1 * 65536 + 256);
      const float2 va2 = *(const float2*)(g + 2 * 65536);
      const float2 vb2 = *(const float2*)(g + 2 * 65536 + 256);
      const float2 va3 = *(const float2*)(g + 3 * 65536);
      const float2 vb3 = *(const float2*)(g + 3 * 65536 + 256);
      const float u0 = (va0.x + va0.y) + (vb0.x + vb0.y);
      const float u1 = (va1.x + va1.y) + (vb1.x + vb1.y);
      const float u2 = (va2.x + va2.y) + (vb2.x + vb2.y);
      const float u3 = (va3.x + va3.y) + (vb3.x + vb3.y);
#pragma unroll
      for (int r = 0; r < 32; ++r) {
        float acc = qa[r];
        acc = fmaf(wq[(i0 + 0) * 32 + r], u0, acc);
        acc = fmaf(wq[(i0 + 1) * 32 + r], u1, acc);
        acc = fmaf(wq[(i0 + 2) * 32 + r], u2, acc);
        acc = fmaf(wq[(i0 + 3) * 32 + r], u3, acc);
        qa[r] = acc;
      }
      g += 4 * 65536;
    }
  }

  // ---- tree-reduce Q across the 4 groups ([r][p]: 2 lanes/bank = free) ----
  if (grp >= 2) {
#pragma unroll
    for (int r = 0; r < 32; ++r) Qpart[(grp - 2) * 2048 + r * 64 + p] = qa[r];
  }
  __syncthreads();
  if (grp < 2) {
#pragma unroll
    for (int r = 0; r < 32; ++r) {
      const float t = qa[r] + Qpart[grp * 2048 + r * 64 + p];
      Qpart[grp * 2048 + r * 64 + p] = t;
    }
  }
  __syncthreads();
#pragma unroll
  for (int r = 0; r < 32; ++r)
    qa[r] = Qpart[r * 64 + p] + Qpart[2048 + r * 64 + p];

  // ---- pass 2: logits over this group's channels (reverse: MRU) ----
  float l0 = 0.f, l1 = 0.f, l2 = 0.f, l3 = 0.f;
  {
    const float* g = gbase + (size_t)28 * 65536;
#pragma unroll 2
    for (int i0 = 28; i0 >= 0; i0 -= 4) {
      const float2 va0 = *(const float2*)(g + 0 * 65536);
      const float2 vb0 = *(const float2*)(g + 0 * 65536 + 256);
      const float2 va1 = *(const float2*)(g + 1 * 65536);
      const float2 vb1 = *(const float2*)(g + 1 * 65536 + 256);
      const float2 va2 = *(const float2*)(g + 2 * 65536);
      const float2 vb2 = *(const float2*)(g + 2 * 65536 + 256);
      const float2 va3 = *(const float2*)(g + 3 * 65536);
      const float2 vb3 = *(const float2*)(g + 3 * 65536 + 256);
#pragma unroll
      for (int j = 0; j < 4; ++j) {
        const int c = i0 + j;
        float t0 = 0.f, t1 = 0.f, t2 = 0.f, t3 = 0.f;
#pragma unroll
        for (int r = 0; r < 32; r += 4) {
          t0 = fmaf(qa[r + 0], wk[c * 32 + r + 0], t0);
          t1 = fmaf(qa[r + 1], wk[c * 32 + r + 1], t1);
          t2 = fmaf(qa[r + 2], wk[c * 32 + r + 2], t2);
          t3 = fmaf(qa[r + 3], wk[c * 32 + r + 3], t3);
        }
        const float tv = (t0 + t1) + (t2 + t3);
        const float2 va = (j == 0) ? va0 : (j == 1) ? va1 : (j == 2) ? va2 : va3;
        const float2 vb = (j == 0) ? vb0 : (j == 1) ? vb1 : (j == 2) ? vb2 : vb3;
        l0 = fmaf(tv, va.x, l0);
        l1 = fmaf(tv, va.y, l1);
        l2 = fmaf(tv, vb.x, l2);
        l3 = fmaf(tv, vb.y, l3);
      }
      g -= 4 * 65536;
    }
  }
  *(float4*)(lbuf + (grp * 64 + p) * 4) = make_float4(l0, l1, l2, l3);
  __syncthreads();

  // ---- softmax (group 0 combines all 4 groups, broadcasts via lbuf[0]) ----
  if (grp == 0) {
    const float4 o1 = *(const float4*)(lbuf + (64 + p) * 4);
    const float4 o2 = *(const float4*)(lbuf + (128 + p) * 4);
    const float4 o3 = *(const float4*)(lbuf + (192 + p) * 4);
    const float L0 = (l0 + o1.x) + (o2.x + o3.x);
    const float L1 = (l1 + o1.y) + (o2.y + o3.y);
    const float L2 = (l2 + o1.z) + (o2.z + o3.z);
    const float L3 = (l3 + o1.w) + (o2.w + o3.w);
    const float mx = fmaxf(fmaxf(L0, L1), fmaxf(L2, L3));
    const float e0 = __expf(L0 - mx), e1 = __expf(L1 - mx);
    const float e2 = __expf(L2 - mx), e3 = __expf(L3 - mx);
    const float inv = 1.0f / ((e0 + e1) + (e2 + e3));
    *(float4*)(lbuf + p * 4) =
        make_float4(e0 * inv, e1 * inv, e2 * inv, e3 * inv);
  }
  __syncthreads();
  const float4 at = *(const float4*)(lbuf + p * 4);

  // ---- pass 3: weighted window sum -> out (forward: MRU after pass 2) ----
  {
    const float* g = gbase;
    float* op = out + ((size_t)(b * 128 + cb) * 16384) + h * 128 + w0 + p;
#pragma unroll 2
    for (int i0 = 0; i0 < 32; i0 += 4) {
      const float2 va0 = *(const float2*)(g + 0 * 65536);
      const float2 vb0 = *(const float2*)(g + 0 * 65536 + 256);
      const float2 va1 = *(const float2*)(g + 1 * 65536);
      const float2 vb1 = *(const float2*)(g + 1 * 65536 + 256);
      const float2 va2 = *(const float2*)(g + 2 * 65536);
      const float2 vb2 = *(const float2*)(g + 2 * 65536 + 256);
      const float2 va3 = *(const float2*)(g + 3 * 65536);
      const float2 vb3 = *(const float2*)(g + 3 * 65536 + 256);
      const float o0 = fmaf(at.x, va0.x, fmaf(at.y, va0.y, fmaf(at.z, vb0.x, at.w * vb0.y)));
      const float o1 = fmaf(at.x, va1.x, fmaf(at.y, va1.y, fmaf(at.z, vb1.x, at.w * vb1.y)));
      const float o2 = fmaf(at.x, va2.x, fmaf(at.y, va2.y, fmaf(at.z, vb2.x, at.w * vb2.y)));
      const float o3 = fmaf(at.x, va3.x, fmaf(at.y, va3.y, fmaf(at.z, vb3.x, at.w * vb3.y)));
      __builtin_nontemporal_store(o0, op);
      __builtin_nontemporal_store(o1, op + 16384);
      __builtin_nontemporal_store(o2, op + 2 * 16384);
      __builtin_nontemporal_store(o3, op + 3 * 16384);
      g += 4 * 65536;
      op += 4 * 16384;
    }
  }
}

extern "C" void kernel_launch(void* const* d_in, const int* in_sizes, int n_in,
                              void* d_out, int out_size, void* d_ws, size_t ws_size,
                              hipStream_t stream) {
  const float* fm = (const float*)d_in[0];
  const float* Wq = (const float*)d_in[1];
  const float* Wk = (const float*)d_in[2];
  float* outp = (float*)d_out;
  float* ws = (float*)d_ws;

  wt_kernel<<<16, 256, 0, stream>>>(Wq, Wk, ws);
  attn_main<<<2048, 256, 0, stream>>>(fm, ws, outp);
}